// Round 8
// baseline (219.936 us; speedup 1.0000x reference)
//
#include <hip/hip_runtime.h>

#define BB 2
#define TT 2048
#define DD 1024
#define HH 16
#define DHD 64
#define MM (BB*TT)   // 4096

typedef __attribute__((ext_vector_type(8))) short short8;
typedef __attribute__((ext_vector_type(4))) float float4v;
typedef unsigned short u16;

__device__ inline float bf2f(u16 u) {
    union { unsigned int i; float f; } v;
    v.i = ((unsigned int)u) << 16;
    return v.f;
}
__device__ inline u16 f2bf(float f) {
    union { float f; unsigned int i; } v;
    v.f = f;
    unsigned int x = v.i;
    unsigned int r = (x + 0x7fffu + ((x >> 16) & 1u)) >> 16;
    return (u16)r;
}

// direct global->LDS copy, 16B per lane; ldst must be wave-uniform (HW: base + lane*16)
__device__ __forceinline__ void gld_lds16(const u16* g, u16* l) {
    __builtin_amdgcn_global_load_lds((const __attribute__((address_space(1))) void*)g,
                                     (__attribute__((address_space(3))) void*)l, 16, 0, 0);
}

// ---------------- prep: cast x to bf16 ----------------
__global__ __launch_bounds__(256) void cast_x_k(const float* __restrict__ x,
                                                u16* __restrict__ xb) {
    int i = blockIdx.x * 256 + threadIdx.x;   // 4 elems/thread
    float4v v = ((const float4v*)x)[i];
    ushort4 o;
    o.x = f2bf(v[0]); o.y = f2bf(v[1]); o.z = f2bf(v[2]); o.w = f2bf(v[3]);
    ((ushort4*)xb)[i] = o;
}

// ---------------- prep: cast + transpose weights (K,N)->(N,K) bf16 ----------------
__global__ __launch_bounds__(256) void transw_k(const float* __restrict__ Wq,
                                                const float* __restrict__ Wk,
                                                const float* __restrict__ Wv,
                                                const float* __restrict__ Wo,
                                                u16* __restrict__ WT) {
    __shared__ u16 t[32][33];
    int wsel = blockIdx.z;
    const float* W = (wsel == 0) ? Wq : (wsel == 1) ? Wk : (wsel == 2) ? Wv : Wo;
    u16* o = WT + (size_t)wsel * DD * DD;
    int k0 = blockIdx.y * 32, n0 = blockIdx.x * 32;
    int tx = threadIdx.x, ty = threadIdx.y;   // 32 x 8
#pragma unroll
    for (int i = 0; i < 4; i++) {
        int k = ty + i * 8;
        t[k][tx] = f2bf(W[(size_t)(k0 + k) * DD + n0 + tx]);
    }
    __syncthreads();
#pragma unroll
    for (int i = 0; i < 4; i++) {
        int n = ty + i * 8;
        o[(size_t)(n0 + n) * DD + k0 + tx] = t[tx][n];
    }
}

// ---------------- GEMM: C(M=4096,N=1024) = A(bf16, MxK) * W (via WT: N,K bf16) ----------------
// m97-style: global_load_lds width=16 staging into UNPADDED [128][32] tiles,
// with an XOR chunk swizzle (LDS chunk c of row r = global chunk c^((r>>1)&3))
// so ds_read_b128 fragment reads are 2-way-bank-aliased only (free).
// MODE 0: out = QKV workspace. z=0: Q (b,h,t,dh); z=1: K (b,h,t,dh); z=2: V^T (b,h,dh,t)
// MODE 1: out = fp32 (M, N) plain
template <int MODE>
__global__ __launch_bounds__(256) void gemm_k(const u16* __restrict__ A,
                                              const u16* __restrict__ WT0,
                                              void* __restrict__ outp) {
    const int K = DD;
    int z = blockIdx.z;
    const u16* WT = WT0 + (size_t)z * DD * DD;
    int n0 = blockIdx.x * 128, m0 = blockIdx.y * 128;

    __shared__ u16 As[128 * 32];
    __shared__ u16 Bs[128 * 32];

    int tid = threadIdx.x;
    int lane = tid & 63, w = tid >> 6;
    int wm = (w >> 1) * 64, wn = (w & 1) * 64;
    int quad = lane >> 4, l16 = lane & 15;

    // staging geometry: wave w covers rows [32w,32w+32) in 2 insts of 16 rows;
    // lane i -> row_local=i>>2, chunk=i&3 (16B chunks of the 64B row)
    int rl = lane >> 2, chk = lane & 3;
    int row0 = w * 32 + rl, row1 = row0 + 16;
    int gch0 = chk ^ ((row0 >> 1) & 3);
    int gch1 = chk ^ ((row1 >> 1) & 3);
    const u16* gA0 = A + (size_t)(m0 + row0) * K + gch0 * 8;
    const u16* gA1 = A + (size_t)(m0 + row1) * K + gch1 * 8;
    const u16* gB0 = WT + (size_t)(n0 + row0) * K + gch0 * 8;
    const u16* gB1 = WT + (size_t)(n0 + row1) * K + gch1 * 8;
    u16* lA0 = As + (w * 32) * 32;        // wave-uniform LDS bases
    u16* lA1 = As + (w * 32 + 16) * 32;
    u16* lB0 = Bs + (w * 32) * 32;
    u16* lB1 = Bs + (w * 32 + 16) * 32;

    // fragment-read swizzle: row = wm/wn + mt*16 + l16; (row>>1)&3 == (l16>>1)&3
    int swz = (l16 >> 1) & 3;
    int cq = (quad ^ swz) * 8;

    float4v acc[4][4];
#pragma unroll
    for (int i = 0; i < 4; i++)
#pragma unroll
        for (int j = 0; j < 4; j++) acc[i][j] = (float4v)(0.0f);

    for (int k0 = 0; k0 < K; k0 += 32) {
        __syncthreads();   // prior iter's fragment reads complete
        gld_lds16(gA0 + k0, lA0);
        gld_lds16(gA1 + k0, lA1);
        gld_lds16(gB0 + k0, lB0);
        gld_lds16(gB1 + k0, lB1);
        __syncthreads();   // vmcnt(0) drain (compiler) -> tile valid

        short8 a[4], b[4];
#pragma unroll
        for (int mt = 0; mt < 4; mt++)
            a[mt] = *(const short8*)&As[(wm + mt * 16 + l16) * 32 + cq];
#pragma unroll
        for (int nt = 0; nt < 4; nt++)
            b[nt] = *(const short8*)&Bs[(wn + nt * 16 + l16) * 32 + cq];
#pragma unroll
        for (int mt = 0; mt < 4; mt++)
#pragma unroll
            for (int nt = 0; nt < 4; nt++)
                acc[mt][nt] = __builtin_amdgcn_mfma_f32_16x16x32_bf16(
                    a[mt], b[nt], acc[mt][nt], 0, 0, 0);
    }

#pragma unroll
    for (int mt = 0; mt < 4; mt++) {
#pragma unroll
        for (int nt = 0; nt < 4; nt++) {
#pragma unroll
            for (int r = 0; r < 4; r++) {
                int m = m0 + wm + mt * 16 + quad * 4 + r;
                int n = n0 + wn + nt * 16 + l16;
                float v = acc[mt][nt][r];
                if constexpr (MODE == 0) {
                    int bb = m >> 11, t = m & 2047;
                    int h = n >> 6, dh = n & 63;
                    size_t idx;
                    if (z == 2)   // V stored transposed: (b,h,dh,t)
                        idx = (((size_t)2 * BB * HH + bb * HH + h) * DHD + dh) * TT + t;
                    else
                        idx = (((size_t)z * BB * HH + bb * HH + h) * TT + t) * DHD + dh;
                    ((u16*)outp)[idx] = f2bf(v);
                } else {
                    ((float*)outp)[(size_t)m * DD + n] = v;
                }
            }
        }
    }
}

// ---------------- flash attention (S^T trick, no-max, paired q-tiles, KV dbuf) ----------------
// Computes S^T = K·Q^T by swapping MFMA operands (A/B frags have identical lane
// maps -> same LDS reads). S^T's C-layout gives each lane (q=l16, kv=quad*4+r+16ct),
// so the P transpose to A-layout is 4 vectorized ds_write_b64 instead of 16 b16.
// Block (p,bh) does q-tiles p and 31-p: 33 KV-iterations for every block.
__global__ __launch_bounds__(256) void attn_k(const u16* __restrict__ QKV,
                                              u16* __restrict__ AO) {
    const u16* Q  = QKV;
    const u16* Kp = QKV + (size_t)MM * DD;
    const u16* Vp = QKV + (size_t)2 * MM * DD;   // V^T: per head [DHD][TT]
    int bh = blockIdx.y;
    int p  = blockIdx.x;          // 0..15
    int qA = p, qB = 31 - p;
    size_t hoff = (size_t)bh * TT * DHD;

    __shared__ u16 Qs[2][64][72];
    __shared__ u16 Ks[2][64][72];
    __shared__ u16 VTs[2][64][72];   // [dh][kv]
    __shared__ u16 Ps[4][16][72];    // per-wave [q][kv]

    int tid = threadIdx.x;
    int lane = tid & 63, w = tid >> 6;
    int quad = lane >> 4, l16 = lane & 15;

    int srow[4], scc[4];
#pragma unroll
    for (int i = 0; i < 4; i++) {
        int c = tid + i * 256;
        srow[i] = c >> 4;
        scc[i]  = (c & 15) * 4;
    }

    // stage BOTH Q tiles, pre-scaled by (1/sqrt(DH)) * log2(e)
    const float qscale = 0.125f * 1.4426950408889634f;
#pragma unroll
    for (int t = 0; t < 2; t++) {
        int q0 = (t ? qB : qA) * 64;
#pragma unroll
        for (int i = 0; i < 4; i++) {
            ushort4 v = *(const ushort4*)(Q + hoff + (size_t)(q0 + srow[i]) * DHD + scc[i]);
            ushort4 sv;
            sv.x = f2bf(bf2f(v.x) * qscale);
            sv.y = f2bf(bf2f(v.y) * qscale);
            sv.z = f2bf(bf2f(v.z) * qscale);
            sv.w = f2bf(bf2f(v.w) * qscale);
            *(ushort4*)&Qs[t][srow[i]][scc[i]] = sv;
        }
    }

    ushort4 kreg[4], vreg[4];
#pragma unroll
    for (int i = 0; i < 4; i++) {   // prefetch KV tile 0 (phase A)
        kreg[i] = *(const ushort4*)(Kp + hoff + (size_t)srow[i] * DHD + scc[i]);
        vreg[i] = *(const ushort4*)(Vp + hoff + (size_t)srow[i] * TT + scc[i]);
    }

    __syncthreads();   // Qs staged
    short8 aqA0 = *(const short8*)&Qs[0][w * 16 + l16][quad * 8];
    short8 aqA1 = *(const short8*)&Qs[0][w * 16 + l16][32 + quad * 8];
    short8 aqB0 = *(const short8*)&Qs[1][w * 16 + l16][quad * 8];
    short8 aqB1 = *(const short8*)&Qs[1][w * 16 + l16][32 + quad * 8];

    int b = bh >> 4, h = bh & 15;
    int it = 0;   // global iteration counter -> LDS buffer parity

#pragma unroll 1
    for (int phase = 0; phase < 2; phase++) {
        int qt = phase ? qB : qA;
        int ntile = qt + 1;
        short8 aq0 = phase ? aqB0 : aqA0;
        short8 aq1 = phase ? aqB1 : aqA1;

        float4v o[4];
#pragma unroll
        for (int i = 0; i < 4; i++) o[i] = (float4v)(0.0f);
        float lr = 0.0f;   // per-lane partial row sum (q = w*16 + l16)

#pragma unroll 1
        for (int jt = 0; jt < ntile; jt++, it++) {
            int db = it & 1;
#pragma unroll
            for (int i = 0; i < 4; i++) {
                *(ushort4*)&Ks[db][srow[i]][scc[i]]  = kreg[i];
                *(ushort4*)&VTs[db][srow[i]][scc[i]] = vreg[i];
            }
            __syncthreads();

            bool last = (phase == 1) && (jt == ntile - 1);
            if (!last) {
                int nj = (jt + 1 < ntile) ? (jt + 1) * 64 : 0;
#pragma unroll
                for (int i = 0; i < 4; i++) {
                    kreg[i] = *(const ushort4*)(Kp + hoff + (size_t)(nj + srow[i]) * DHD + scc[i]);
                    vreg[i] = *(const ushort4*)(Vp + hoff + (size_t)srow[i] * TT + nj + scc[i]);
                }
            }

            // S^T (64 kv x 16 q per wave) = K·Q^T: same LDS reads, swapped operands
            float4v s[4];
#pragma unroll
            for (int ct = 0; ct < 4; ct++) {
                short8 ak0 = *(const short8*)&Ks[db][ct * 16 + l16][quad * 8];
                short8 ak1 = *(const short8*)&Ks[db][ct * 16 + l16][32 + quad * 8];
                float4v sv = (float4v)(0.0f);
                sv = __builtin_amdgcn_mfma_f32_16x16x32_bf16(ak0, aq0, sv, 0, 0, 0);
                sv = __builtin_amdgcn_mfma_f32_16x16x32_bf16(ak1, aq1, sv, 0, 0, 0);
                s[ct] = sv;   // row=quad*4+r -> kv_local(ct block); col=l16 -> q_local
            }

            if (jt == ntile - 1) {   // diagonal tile: mask kv > q
                int ql = w * 16 + l16;
#pragma unroll
                for (int ct = 0; ct < 4; ct++)
#pragma unroll
                    for (int r = 0; r < 4; r++) {
                        int kvl = ct * 16 + quad * 4 + r;
                        if (kvl > ql) s[ct][r] = -30000.0f;
                    }
            }

            // p = exp2(s); vectorized P write: 4 consecutive kv per (ct) -> ushort4
#pragma unroll
            for (int ct = 0; ct < 4; ct++) {
                float p0 = exp2f(s[ct][0]);
                float p1 = exp2f(s[ct][1]);
                float p2 = exp2f(s[ct][2]);
                float p3 = exp2f(s[ct][3]);
                lr += (p0 + p1) + (p2 + p3);
                union { float f; unsigned u; } c0, c1, c2, c3;
                c0.f = p0; c1.f = p1; c2.f = p2; c3.f = p3;
                ushort4 pw;
                pw.x = (u16)(c0.u >> 16);
                pw.y = (u16)(c1.u >> 16);
                pw.z = (u16)(c2.u >> 16);
                pw.w = (u16)(c3.u >> 16);
                *(ushort4*)&Ps[w][l16][ct * 16 + quad * 4] = pw;
            }

            short8 ap0 = *(const short8*)&Ps[w][l16][quad * 8];
            short8 ap1 = *(const short8*)&Ps[w][l16][32 + quad * 8];
#pragma unroll
            for (int ct = 0; ct < 4; ct++) {
                short8 bv0 = *(const short8*)&VTs[db][ct * 16 + l16][quad * 8];
                short8 bv1 = *(const short8*)&VTs[db][ct * 16 + l16][32 + quad * 8];
                o[ct] = __builtin_amdgcn_mfma_f32_16x16x32_bf16(ap0, bv0, o[ct], 0, 0, 0);
                o[ct] = __builtin_amdgcn_mfma_f32_16x16x32_bf16(ap1, bv1, o[ct], 0, 0, 0);
            }
        }

        // reduce row sums across quads (lane holds q = w*16 + l16)
        float rs = lr;
        rs += __shfl_xor(rs, 16);
        rs += __shfl_xor(rs, 32);
        // redistribute: epilogue lane needs sums for q_local = quad*4 + r
        int gbase = lane & 48;   // own 16-lane group
        float rinv[4];
#pragma unroll
        for (int r = 0; r < 4; r++)
            rinv[r] = 1.0f / __shfl(rs, gbase + quad * 4 + r);

        int q0 = qt * 64;
#pragma unroll
        for (int ct = 0; ct < 4; ct++) {
#pragma unroll
            for (int r = 0; r < 4; r++) {
                int q = q0 + w * 16 + quad * 4 + r;
                int d = h * 64 + ct * 16 + l16;
                AO[(size_t)(b * TT + q) * DD + d] = f2bf(o[ct][r] * rinv[r]);
            }
        }
    }
}

extern "C" void kernel_launch(void* const* d_in, const int* in_sizes, int n_in,
                              void* d_out, int out_size, void* d_ws, size_t ws_size,
                              hipStream_t stream) {
    const float* x  = (const float*)d_in[0];
    const float* Wq = (const float*)d_in[1];
    const float* Wk = (const float*)d_in[2];
    const float* Wv = (const float*)d_in[3];
    const float* Wo = (const float*)d_in[4];

    u16* xb  = (u16*)d_ws;                       // 8 MB  : x in bf16
    u16* WT  = xb + (size_t)MM * DD;             // 8 MB  : 4 transposed weights bf16
    u16* QKV = WT + (size_t)4 * DD * DD;         // 24 MB : Q,K (b,h,t,dh) + V^T (b,h,dh,t)
    u16* AO  = QKV + (size_t)3 * MM * DD;        // 8 MB  : attention out (B,T,D) bf16
    float* out = (float*)d_out;

    cast_x_k<<<dim3(MM * DD / 1024), 256, 0, stream>>>(x, xb);
    transw_k<<<dim3(32, 32, 4), dim3(32, 8), 0, stream>>>(Wq, Wk, Wv, Wo, WT);
    gemm_k<0><<<dim3(8, 32, 3), 256, 0, stream>>>(xb, WT, QKV);
    attn_k<<<dim3(16, 32), 256, 0, stream>>>(QKV, AO);
    gemm_k<1><<<dim3(8, 32, 1), 256, 0, stream>>>(AO, WT + (size_t)3 * DD * DD, out);
}

// Round 9
// 210.603 us; speedup vs baseline: 1.0443x; 1.0443x over previous
//
#include <hip/hip_runtime.h>

#define BB 2
#define TT 2048
#define DD 1024
#define HH 16
#define DHD 64
#define MM (BB*TT)   // 4096

typedef __attribute__((ext_vector_type(8))) short short8;
typedef __attribute__((ext_vector_type(4))) float float4v;
typedef unsigned short u16;

__device__ inline float bf2f(u16 u) {
    union { unsigned int i; float f; } v;
    v.i = ((unsigned int)u) << 16;
    return v.f;
}
__device__ inline u16 f2bf(float f) {
    union { float f; unsigned int i; } v;
    v.f = f;
    unsigned int x = v.i;
    unsigned int r = (x + 0x7fffu + ((x >> 16) & 1u)) >> 16;
    return (u16)r;
}

// direct global->LDS copy, 16B per lane; lds dst is wave-uniform base + lane*16
__device__ __forceinline__ void gld_lds16(const u16* g, u16* l) {
    __builtin_amdgcn_global_load_lds((const __attribute__((address_space(1))) void*)g,
                                     (__attribute__((address_space(3))) void*)l, 16, 0, 0);
}

// ---------------- prep: cast x to bf16 ----------------
__global__ __launch_bounds__(256) void cast_x_k(const float* __restrict__ x,
                                                u16* __restrict__ xb) {
    int i = blockIdx.x * 256 + threadIdx.x;   // 4 elems/thread
    float4v v = ((const float4v*)x)[i];
    ushort4 o;
    o.x = f2bf(v[0]); o.y = f2bf(v[1]); o.z = f2bf(v[2]); o.w = f2bf(v[3]);
    ((ushort4*)xb)[i] = o;
}

// ---------------- prep: cast + transpose weights (K,N)->(N,K) bf16 ----------------
__global__ __launch_bounds__(256) void transw_k(const float* __restrict__ Wq,
                                                const float* __restrict__ Wk,
                                                const float* __restrict__ Wv,
                                                const float* __restrict__ Wo,
                                                u16* __restrict__ WT) {
    __shared__ u16 t[32][33];
    int wsel = blockIdx.z;
    const float* W = (wsel == 0) ? Wq : (wsel == 1) ? Wk : (wsel == 2) ? Wv : Wo;
    u16* o = WT + (size_t)wsel * DD * DD;
    int k0 = blockIdx.y * 32, n0 = blockIdx.x * 32;
    int tx = threadIdx.x, ty = threadIdx.y;   // 32 x 8
#pragma unroll
    for (int i = 0; i < 4; i++) {
        int k = ty + i * 8;
        t[k][tx] = f2bf(W[(size_t)(k0 + k) * DD + n0 + tx]);
    }
    __syncthreads();
#pragma unroll
    for (int i = 0; i < 4; i++) {
        int n = ty + i * 8;
        o[(size_t)(n0 + n) * DD + k0 + tx] = t[tx][n];
    }
}

// ---------------- GEMM: C(M=4096,N=1024) = A(bf16, MxK) * W (via WT: N,K bf16) ----------------
// global_load_lds width=16 staging into DOUBLE-BUFFERED unpadded [128][32] tiles.
// XOR chunk swizzle (LDS chunk c of row r = global chunk c^((r>>1)&3)) keeps
// ds_read_b128 fragment reads 2-way-bank-aliased (free). One barrier per K-iter;
// DMA for tile k+1 is in flight during tile k's MFMA (drained at next barrier).
// MODE 0: out = QKV workspace. z=0: Q (b,h,t,dh); z=1: K (b,h,t,dh); z=2: V^T (b,h,dh,t)
// MODE 1: out = fp32 (M, N) plain
template <int MODE>
__global__ __launch_bounds__(256) void gemm_k(const u16* __restrict__ A,
                                              const u16* __restrict__ WT0,
                                              void* __restrict__ outp) {
    const int K = DD;
    int z = blockIdx.z;
    const u16* WT = WT0 + (size_t)z * DD * DD;
    int n0 = blockIdx.x * 128, m0 = blockIdx.y * 128;

    __shared__ u16 As[2][128 * 32];
    __shared__ u16 Bs[2][128 * 32];

    int tid = threadIdx.x;
    int lane = tid & 63, w = tid >> 6;
    int wm = (w >> 1) * 64, wn = (w & 1) * 64;
    int quad = lane >> 4, l16 = lane & 15;

    // staging geometry: wave w covers rows [32w,32w+32) in 2 insts of 16 rows;
    // lane i -> row_local=i>>2, chunk=i&3 (16B chunks of the 64B k-slab)
    int rl = lane >> 2, chk = lane & 3;
    int row0 = w * 32 + rl, row1 = row0 + 16;
    int gch0 = chk ^ ((row0 >> 1) & 3);
    int gch1 = chk ^ ((row1 >> 1) & 3);
    const u16* gA0 = A + (size_t)(m0 + row0) * K + gch0 * 8;
    const u16* gA1 = A + (size_t)(m0 + row1) * K + gch1 * 8;
    const u16* gB0 = WT + (size_t)(n0 + row0) * K + gch0 * 8;
    const u16* gB1 = WT + (size_t)(n0 + row1) * K + gch1 * 8;
    int off0 = (w * 32) * 32;          // wave-uniform LDS offsets
    int off1 = (w * 32 + 16) * 32;

    // fragment-read swizzle: row = wm/wn + mt*16 + l16; (row>>1)&3 == (l16>>1)&3
    int cq = (quad ^ ((l16 >> 1) & 3)) * 8;

    float4v acc[4][4];
#pragma unroll
    for (int i = 0; i < 4; i++)
#pragma unroll
        for (int j = 0; j < 4; j++) acc[i][j] = (float4v)(0.0f);

    // prologue: DMA tile 0 into buffer 0
    gld_lds16(gA0, As[0] + off0);
    gld_lds16(gA1, As[0] + off1);
    gld_lds16(gB0, Bs[0] + off0);
    gld_lds16(gB1, Bs[0] + off1);

    const int NK = K / 32;
#pragma unroll 1
    for (int ki = 0; ki < NK; ki++) {
        int p = ki & 1;
        __syncthreads();   // drains DMA for tile ki (and iter ki-1's ds_reads)

        if (ki + 1 < NK) {   // DMA tile ki+1 into other buffer; in flight during MFMA
            int k0 = (ki + 1) * 32;
            gld_lds16(gA0 + k0, As[p ^ 1] + off0);
            gld_lds16(gA1 + k0, As[p ^ 1] + off1);
            gld_lds16(gB0 + k0, Bs[p ^ 1] + off0);
            gld_lds16(gB1 + k0, Bs[p ^ 1] + off1);
        }

        short8 a[4], b[4];
#pragma unroll
        for (int mt = 0; mt < 4; mt++)
            a[mt] = *(const short8*)&As[p][(wm + mt * 16 + l16) * 32 + cq];
#pragma unroll
        for (int nt = 0; nt < 4; nt++)
            b[nt] = *(const short8*)&Bs[p][(wn + nt * 16 + l16) * 32 + cq];
#pragma unroll
        for (int mt = 0; mt < 4; mt++)
#pragma unroll
            for (int nt = 0; nt < 4; nt++)
                acc[mt][nt] = __builtin_amdgcn_mfma_f32_16x16x32_bf16(
                    a[mt], b[nt], acc[mt][nt], 0, 0, 0);
    }

#pragma unroll
    for (int mt = 0; mt < 4; mt++) {
#pragma unroll
        for (int nt = 0; nt < 4; nt++) {
#pragma unroll
            for (int r = 0; r < 4; r++) {
                int m = m0 + wm + mt * 16 + quad * 4 + r;
                int n = n0 + wn + nt * 16 + l16;
                float v = acc[mt][nt][r];
                if constexpr (MODE == 0) {
                    int bb = m >> 11, t = m & 2047;
                    int h = n >> 6, dh = n & 63;
                    size_t idx;
                    if (z == 2)   // V stored transposed: (b,h,dh,t)
                        idx = (((size_t)2 * BB * HH + bb * HH + h) * DHD + dh) * TT + t;
                    else
                        idx = (((size_t)z * BB * HH + bb * HH + h) * TT + t) * DHD + dh;
                    ((u16*)outp)[idx] = f2bf(v);
                } else {
                    ((float*)outp)[(size_t)m * DD + n] = v;
                }
            }
        }
    }
}

// ---------------- flash attention (S^T trick, no-max, paired q-tiles, KV dbuf) ----------------
__global__ __launch_bounds__(256) void attn_k(const u16* __restrict__ QKV,
                                              u16* __restrict__ AO) {
    const u16* Q  = QKV;
    const u16* Kp = QKV + (size_t)MM * DD;
    const u16* Vp = QKV + (size_t)2 * MM * DD;   // V^T: per head [DHD][TT]
    int bh = blockIdx.y;
    int p  = blockIdx.x;          // 0..15
    int qA = p, qB = 31 - p;
    size_t hoff = (size_t)bh * TT * DHD;

    __shared__ u16 Qs[2][64][72];
    __shared__ u16 Ks[2][64][72];
    __shared__ u16 VTs[2][64][72];   // [dh][kv]
    __shared__ u16 Ps[4][16][72];    // per-wave [q][kv]

    int tid = threadIdx.x;
    int lane = tid & 63, w = tid >> 6;
    int quad = lane >> 4, l16 = lane & 15;

    int srow[4], scc[4];
#pragma unroll
    for (int i = 0; i < 4; i++) {
        int c = tid + i * 256;
        srow[i] = c >> 4;
        scc[i]  = (c & 15) * 4;
    }

    // stage BOTH Q tiles, pre-scaled by (1/sqrt(DH)) * log2(e)
    const float qscale = 0.125f * 1.4426950408889634f;
#pragma unroll
    for (int t = 0; t < 2; t++) {
        int q0 = (t ? qB : qA) * 64;
#pragma unroll
        for (int i = 0; i < 4; i++) {
            ushort4 v = *(const ushort4*)(Q + hoff + (size_t)(q0 + srow[i]) * DHD + scc[i]);
            ushort4 sv;
            sv.x = f2bf(bf2f(v.x) * qscale);
            sv.y = f2bf(bf2f(v.y) * qscale);
            sv.z = f2bf(bf2f(v.z) * qscale);
            sv.w = f2bf(bf2f(v.w) * qscale);
            *(ushort4*)&Qs[t][srow[i]][scc[i]] = sv;
        }
    }

    ushort4 kreg[4], vreg[4];
#pragma unroll
    for (int i = 0; i < 4; i++) {   // prefetch KV tile 0 (phase A)
        kreg[i] = *(const ushort4*)(Kp + hoff + (size_t)srow[i] * DHD + scc[i]);
        vreg[i] = *(const ushort4*)(Vp + hoff + (size_t)srow[i] * TT + scc[i]);
    }

    __syncthreads();   // Qs staged
    short8 aqA0 = *(const short8*)&Qs[0][w * 16 + l16][quad * 8];
    short8 aqA1 = *(const short8*)&Qs[0][w * 16 + l16][32 + quad * 8];
    short8 aqB0 = *(const short8*)&Qs[1][w * 16 + l16][quad * 8];
    short8 aqB1 = *(const short8*)&Qs[1][w * 16 + l16][32 + quad * 8];

    int b = bh >> 4, h = bh & 15;
    int it = 0;   // global iteration counter -> LDS buffer parity

#pragma unroll 1
    for (int phase = 0; phase < 2; phase++) {
        int qt = phase ? qB : qA;
        int ntile = qt + 1;
        short8 aq0 = phase ? aqB0 : aqA0;
        short8 aq1 = phase ? aqB1 : aqA1;

        float4v o[4];
#pragma unroll
        for (int i = 0; i < 4; i++) o[i] = (float4v)(0.0f);
        float lr = 0.0f;   // per-lane partial row sum (q = w*16 + l16)

#pragma unroll 1
        for (int jt = 0; jt < ntile; jt++, it++) {
            int db = it & 1;
#pragma unroll
            for (int i = 0; i < 4; i++) {
                *(ushort4*)&Ks[db][srow[i]][scc[i]]  = kreg[i];
                *(ushort4*)&VTs[db][srow[i]][scc[i]] = vreg[i];
            }
            __syncthreads();

            bool last = (phase == 1) && (jt == ntile - 1);
            if (!last) {
                int nj = (jt + 1 < ntile) ? (jt + 1) * 64 : 0;
#pragma unroll
                for (int i = 0; i < 4; i++) {
                    kreg[i] = *(const ushort4*)(Kp + hoff + (size_t)(nj + srow[i]) * DHD + scc[i]);
                    vreg[i] = *(const ushort4*)(Vp + hoff + (size_t)srow[i] * TT + nj + scc[i]);
                }
            }

            // S^T (64 kv x 16 q per wave) = K·Q^T: same LDS reads, swapped operands
            float4v s[4];
#pragma unroll
            for (int ct = 0; ct < 4; ct++) {
                short8 ak0 = *(const short8*)&Ks[db][ct * 16 + l16][quad * 8];
                short8 ak1 = *(const short8*)&Ks[db][ct * 16 + l16][32 + quad * 8];
                float4v sv = (float4v)(0.0f);
                sv = __builtin_amdgcn_mfma_f32_16x16x32_bf16(ak0, aq0, sv, 0, 0, 0);
                sv = __builtin_amdgcn_mfma_f32_16x16x32_bf16(ak1, aq1, sv, 0, 0, 0);
                s[ct] = sv;   // row=quad*4+r -> kv_local(ct block); col=l16 -> q_local
            }

            if (jt == ntile - 1) {   // diagonal tile: mask kv > q
                int ql = w * 16 + l16;
#pragma unroll
                for (int ct = 0; ct < 4; ct++)
#pragma unroll
                    for (int r = 0; r < 4; r++) {
                        int kvl = ct * 16 + quad * 4 + r;
                        if (kvl > ql) s[ct][r] = -30000.0f;
                    }
            }

            // p = exp2(s); vectorized P write: 4 consecutive kv per (ct) -> ushort4
#pragma unroll
            for (int ct = 0; ct < 4; ct++) {
                float p0 = exp2f(s[ct][0]);
                float p1 = exp2f(s[ct][1]);
                float p2 = exp2f(s[ct][2]);
                float p3 = exp2f(s[ct][3]);
                lr += (p0 + p1) + (p2 + p3);
                union { float f; unsigned u; } c0, c1, c2, c3;
                c0.f = p0; c1.f = p1; c2.f = p2; c3.f = p3;
                ushort4 pw;
                pw.x = (u16)(c0.u >> 16);
                pw.y = (u16)(c1.u >> 16);
                pw.z = (u16)(c2.u >> 16);
                pw.w = (u16)(c3.u >> 16);
                *(ushort4*)&Ps[w][l16][ct * 16 + quad * 4] = pw;
            }

            short8 ap0 = *(const short8*)&Ps[w][l16][quad * 8];
            short8 ap1 = *(const short8*)&Ps[w][l16][32 + quad * 8];
#pragma unroll
            for (int ct = 0; ct < 4; ct++) {
                short8 bv0 = *(const short8*)&VTs[db][ct * 16 + l16][quad * 8];
                short8 bv1 = *(const short8*)&VTs[db][ct * 16 + l16][32 + quad * 8];
                o[ct] = __builtin_amdgcn_mfma_f32_16x16x32_bf16(ap0, bv0, o[ct], 0, 0, 0);
                o[ct] = __builtin_amdgcn_mfma_f32_16x16x32_bf16(ap1, bv1, o[ct], 0, 0, 0);
            }
        }

        // reduce row sums across quads (lane holds q = w*16 + l16)
        float rs = lr;
        rs += __shfl_xor(rs, 16);
        rs += __shfl_xor(rs, 32);
        int gbase = lane & 48;
        float rinv[4];
#pragma unroll
        for (int r = 0; r < 4; r++)
            rinv[r] = 1.0f / __shfl(rs, gbase + quad * 4 + r);

        int q0 = qt * 64;
#pragma unroll
        for (int ct = 0; ct < 4; ct++) {
#pragma unroll
            for (int r = 0; r < 4; r++) {
                int q = q0 + w * 16 + quad * 4 + r;
                int d = h * 64 + ct * 16 + l16;
                AO[(size_t)(b * TT + q) * DD + d] = f2bf(o[ct][r] * rinv[r]);
            }
        }
    }
}

extern "C" void kernel_launch(void* const* d_in, const int* in_sizes, int n_in,
                              void* d_out, int out_size, void* d_ws, size_t ws_size,
                              hipStream_t stream) {
    const float* x  = (const float*)d_in[0];
    const float* Wq = (const float*)d_in[1];
    const float* Wk = (const float*)d_in[2];
    const float* Wv = (const float*)d_in[3];
    const float* Wo = (const float*)d_in[4];

    u16* xb  = (u16*)d_ws;                       // 8 MB  : x in bf16
    u16* WT  = xb + (size_t)MM * DD;             // 8 MB  : 4 transposed weights bf16
    u16* QKV = WT + (size_t)4 * DD * DD;         // 24 MB : Q,K (b,h,t,dh) + V^T (b,h,dh,t)
    u16* AO  = QKV + (size_t)3 * MM * DD;        // 8 MB  : attention out (B,T,D) bf16
    float* out = (float*)d_out;

    cast_x_k<<<dim3(MM * DD / 1024), 256, 0, stream>>>(x, xb);
    transw_k<<<dim3(32, 32, 4), dim3(32, 8), 0, stream>>>(Wq, Wk, Wv, Wo, WT);
    gemm_k<0><<<dim3(8, 32, 3), 256, 0, stream>>>(xb, WT, QKV);
    attn_k<<<dim3(16, 32), 256, 0, stream>>>(QKV, AO);
    gemm_k<1><<<dim3(8, 32, 1), 256, 0, stream>>>(AO, WT + (size_t)3 * DD * DD, out);
}

// Round 10
// 209.842 us; speedup vs baseline: 1.0481x; 1.0036x over previous
//
#include <hip/hip_runtime.h>

#define BB 2
#define TT 2048
#define DD 1024
#define HH 16
#define DHD 64
#define MM (BB*TT)   // 4096

typedef __attribute__((ext_vector_type(8))) short short8;
typedef __attribute__((ext_vector_type(4))) float float4v;
typedef unsigned short u16;

__device__ inline float bf2f(u16 u) {
    union { unsigned int i; float f; } v;
    v.i = ((unsigned int)u) << 16;
    return v.f;
}
__device__ inline u16 f2bf(float f) {
    union { float f; unsigned int i; } v;
    v.f = f;
    unsigned int x = v.i;
    unsigned int r = (x + 0x7fffu + ((x >> 16) & 1u)) >> 16;
    return (u16)r;
}

// direct global->LDS copy, 16B per lane; lds dst is wave-uniform base + lane*16
__device__ __forceinline__ void gld_lds16(const u16* g, u16* l) {
    __builtin_amdgcn_global_load_lds((const __attribute__((address_space(1))) void*)g,
                                     (__attribute__((address_space(3))) void*)l, 16, 0, 0);
}

// ---------------- prep: cast x to bf16 ----------------
__global__ __launch_bounds__(256) void cast_x_k(const float* __restrict__ x,
                                                u16* __restrict__ xb) {
    int i = blockIdx.x * 256 + threadIdx.x;   // 4 elems/thread
    float4v v = ((const float4v*)x)[i];
    ushort4 o;
    o.x = f2bf(v[0]); o.y = f2bf(v[1]); o.z = f2bf(v[2]); o.w = f2bf(v[3]);
    ((ushort4*)xb)[i] = o;
}

// ---------------- prep: cast + transpose weights (K,N)->(N,K) bf16 ----------------
__global__ __launch_bounds__(256) void transw_k(const float* __restrict__ Wq,
                                                const float* __restrict__ Wk,
                                                const float* __restrict__ Wv,
                                                const float* __restrict__ Wo,
                                                u16* __restrict__ WT) {
    __shared__ u16 t[32][33];
    int wsel = blockIdx.z;
    const float* W = (wsel == 0) ? Wq : (wsel == 1) ? Wk : (wsel == 2) ? Wv : Wo;
    u16* o = WT + (size_t)wsel * DD * DD;
    int k0 = blockIdx.y * 32, n0 = blockIdx.x * 32;
    int tx = threadIdx.x, ty = threadIdx.y;   // 32 x 8
#pragma unroll
    for (int i = 0; i < 4; i++) {
        int k = ty + i * 8;
        t[k][tx] = f2bf(W[(size_t)(k0 + k) * DD + n0 + tx]);
    }
    __syncthreads();
#pragma unroll
    for (int i = 0; i < 4; i++) {
        int n = ty + i * 8;
        o[(size_t)(n0 + n) * DD + k0 + tx] = t[tx][n];
    }
}

// ---------------- GEMM: C(M,N) = A(bf16, MxK) * W (via WT: N,K bf16), TM x TN tiles --------
// Occupancy-tiled (G1): blocks overlap each other's barrier-drain stalls (r9 evidence:
// 1 vs 3 blocks/CU gave identical duration -> throughput scales with blocks/CU).
// global_load_lds width=16, double-buffered, unified A|B LDS region, XOR chunk
// swizzle (chunk c of row r holds global chunk c^((r>>1)&3)) -> 0 bank conflicts.
// 4 waves in 2x2; wave tile (TM/2)x(TN/2).
// MODE 0: out = QKV workspace. z=0: Q (b,h,t,dh); z=1: K (b,h,t,dh); z=2: V^T (b,h,dh,t)
// MODE 1: out = fp32 (M, N) plain
template <int MODE, int TM, int TN>
__global__ __launch_bounds__(256) void gemm_k(const u16* __restrict__ A,
                                              const u16* __restrict__ WT0,
                                              void* __restrict__ outp) {
    const int K = DD;
    const int MT = TM / 32, NT = TN / 32;        // acc tiles per wave
    const int NA = TM / 16, NB = TN / 16;        // 16-row staging blocks
    const int NS = (NA + NB) / 4;                // DMA insts per wave per buffer

    int z = blockIdx.z;
    const u16* WT = WT0 + (size_t)z * DD * DD;
    int n0 = blockIdx.x * TN, m0 = blockIdx.y * TM;

    __shared__ u16 S[2][(TM + TN) * 32];         // A rows [0,TM), B rows [TM,TM+TN)

    int tid = threadIdx.x;
    int lane = tid & 63, w = tid >> 6;
    int wm = (w >> 1) * (TM / 2), wn = (w & 1) * (TN / 2);
    int quad = lane >> 4, l16 = lane & 15;

    // staging geometry: inst covers 16 rows x 4 chunks (16B each); lane->row rl, chunk chk
    int rl = lane >> 2, chk = lane & 3;
    int gch = chk ^ ((rl >> 1) & 3);             // row-block offsets are x16 -> lane-only
    const u16* gptr[NS];
    int lofs[NS];
#pragma unroll
    for (int j = 0; j < NS; j++) {
        int i = w + j * 4;                        // combined A|B block index
        if (i < NA) gptr[j] = A  + (size_t)(m0 + i * 16 + rl) * K + gch * 8;
        else        gptr[j] = WT + (size_t)(n0 + (i - NA) * 16 + rl) * K + gch * 8;
        lofs[j] = i * 16 * 32;
    }

    // fragment-read swizzle: row = wm/wn + t*16 + l16 -> (row>>1)&3 == (l16>>1)&3
    int cq = (quad ^ ((l16 >> 1) & 3)) * 8;

    float4v acc[MT][NT];
#pragma unroll
    for (int i = 0; i < MT; i++)
#pragma unroll
        for (int j = 0; j < NT; j++) acc[i][j] = (float4v)(0.0f);

    // prologue: DMA tile 0 into buffer 0
#pragma unroll
    for (int j = 0; j < NS; j++) gld_lds16(gptr[j], S[0] + lofs[j]);

    const int NK = K / 32;
#pragma unroll 1
    for (int ki = 0; ki < NK; ki++) {
        int p = ki & 1;
        __syncthreads();   // drains DMA for tile ki + prior-iter frag reads

        if (ki + 1 < NK) {
            int k0 = (ki + 1) * 32;
#pragma unroll
            for (int j = 0; j < NS; j++) gld_lds16(gptr[j] + k0, S[p ^ 1] + lofs[j]);
        }

        short8 a[MT], b[NT];
#pragma unroll
        for (int mt = 0; mt < MT; mt++)
            a[mt] = *(const short8*)&S[p][(wm + mt * 16 + l16) * 32 + cq];
#pragma unroll
        for (int nt = 0; nt < NT; nt++)
            b[nt] = *(const short8*)&S[p][(TM + wn + nt * 16 + l16) * 32 + cq];
#pragma unroll
        for (int mt = 0; mt < MT; mt++)
#pragma unroll
            for (int nt = 0; nt < NT; nt++)
                acc[mt][nt] = __builtin_amdgcn_mfma_f32_16x16x32_bf16(
                    a[mt], b[nt], acc[mt][nt], 0, 0, 0);
    }

#pragma unroll
    for (int mt = 0; mt < MT; mt++) {
#pragma unroll
        for (int nt = 0; nt < NT; nt++) {
#pragma unroll
            for (int r = 0; r < 4; r++) {
                int m = m0 + wm + mt * 16 + quad * 4 + r;
                int n = n0 + wn + nt * 16 + l16;
                float v = acc[mt][nt][r];
                if constexpr (MODE == 0) {
                    int bb = m >> 11, t = m & 2047;
                    int h = n >> 6, dh = n & 63;
                    size_t idx;
                    if (z == 2)   // V stored transposed: (b,h,dh,t)
                        idx = (((size_t)2 * BB * HH + bb * HH + h) * DHD + dh) * TT + t;
                    else
                        idx = (((size_t)z * BB * HH + bb * HH + h) * TT + t) * DHD + dh;
                    ((u16*)outp)[idx] = f2bf(v);
                } else {
                    ((float*)outp)[(size_t)m * DD + n] = v;
                }
            }
        }
    }
}

// ---------------- flash attention (S^T trick, no-max, paired q-tiles, KV dbuf) ----------------
__global__ __launch_bounds__(256) void attn_k(const u16* __restrict__ QKV,
                                              u16* __restrict__ AO) {
    const u16* Q  = QKV;
    const u16* Kp = QKV + (size_t)MM * DD;
    const u16* Vp = QKV + (size_t)2 * MM * DD;   // V^T: per head [DHD][TT]
    int bh = blockIdx.y;
    int p  = blockIdx.x;          // 0..15
    int qA = p, qB = 31 - p;
    size_t hoff = (size_t)bh * TT * DHD;

    __shared__ u16 Qs[2][64][72];
    __shared__ u16 Ks[2][64][72];
    __shared__ u16 VTs[2][64][72];   // [dh][kv]
    __shared__ u16 Ps[4][16][72];    // per-wave [q][kv]

    int tid = threadIdx.x;
    int lane = tid & 63, w = tid >> 6;
    int quad = lane >> 4, l16 = lane & 15;

    int srow[4], scc[4];
#pragma unroll
    for (int i = 0; i < 4; i++) {
        int c = tid + i * 256;
        srow[i] = c >> 4;
        scc[i]  = (c & 15) * 4;
    }

    // stage BOTH Q tiles, pre-scaled by (1/sqrt(DH)) * log2(e)
    const float qscale = 0.125f * 1.4426950408889634f;
#pragma unroll
    for (int t = 0; t < 2; t++) {
        int q0 = (t ? qB : qA) * 64;
#pragma unroll
        for (int i = 0; i < 4; i++) {
            ushort4 v = *(const ushort4*)(Q + hoff + (size_t)(q0 + srow[i]) * DHD + scc[i]);
            ushort4 sv;
            sv.x = f2bf(bf2f(v.x) * qscale);
            sv.y = f2bf(bf2f(v.y) * qscale);
            sv.z = f2bf(bf2f(v.z) * qscale);
            sv.w = f2bf(bf2f(v.w) * qscale);
            *(ushort4*)&Qs[t][srow[i]][scc[i]] = sv;
        }
    }

    ushort4 kreg[4], vreg[4];
#pragma unroll
    for (int i = 0; i < 4; i++) {   // prefetch KV tile 0 (phase A)
        kreg[i] = *(const ushort4*)(Kp + hoff + (size_t)srow[i] * DHD + scc[i]);
        vreg[i] = *(const ushort4*)(Vp + hoff + (size_t)srow[i] * TT + scc[i]);
    }

    __syncthreads();   // Qs staged
    short8 aqA0 = *(const short8*)&Qs[0][w * 16 + l16][quad * 8];
    short8 aqA1 = *(const short8*)&Qs[0][w * 16 + l16][32 + quad * 8];
    short8 aqB0 = *(const short8*)&Qs[1][w * 16 + l16][quad * 8];
    short8 aqB1 = *(const short8*)&Qs[1][w * 16 + l16][32 + quad * 8];

    int b = bh >> 4, h = bh & 15;
    int it = 0;   // global iteration counter -> LDS buffer parity

#pragma unroll 1
    for (int phase = 0; phase < 2; phase++) {
        int qt = phase ? qB : qA;
        int ntile = qt + 1;
        short8 aq0 = phase ? aqB0 : aqA0;
        short8 aq1 = phase ? aqB1 : aqA1;

        float4v o[4];
#pragma unroll
        for (int i = 0; i < 4; i++) o[i] = (float4v)(0.0f);
        float lr = 0.0f;   // per-lane partial row sum (q = w*16 + l16)

#pragma unroll 1
        for (int jt = 0; jt < ntile; jt++, it++) {
            int db = it & 1;
#pragma unroll
            for (int i = 0; i < 4; i++) {
                *(ushort4*)&Ks[db][srow[i]][scc[i]]  = kreg[i];
                *(ushort4*)&VTs[db][srow[i]][scc[i]] = vreg[i];
            }
            __syncthreads();

            bool last = (phase == 1) && (jt == ntile - 1);
            if (!last) {
                int nj = (jt + 1 < ntile) ? (jt + 1) * 64 : 0;
#pragma unroll
                for (int i = 0; i < 4; i++) {
                    kreg[i] = *(const ushort4*)(Kp + hoff + (size_t)(nj + srow[i]) * DHD + scc[i]);
                    vreg[i] = *(const ushort4*)(Vp + hoff + (size_t)srow[i] * TT + nj + scc[i]);
                }
            }

            // S^T (64 kv x 16 q per wave) = K·Q^T: same LDS reads, swapped operands
            float4v s[4];
#pragma unroll
            for (int ct = 0; ct < 4; ct++) {
                short8 ak0 = *(const short8*)&Ks[db][ct * 16 + l16][quad * 8];
                short8 ak1 = *(const short8*)&Ks[db][ct * 16 + l16][32 + quad * 8];
                float4v sv = (float4v)(0.0f);
                sv = __builtin_amdgcn_mfma_f32_16x16x32_bf16(ak0, aq0, sv, 0, 0, 0);
                sv = __builtin_amdgcn_mfma_f32_16x16x32_bf16(ak1, aq1, sv, 0, 0, 0);
                s[ct] = sv;   // row=quad*4+r -> kv_local(ct block); col=l16 -> q_local
            }

            if (jt == ntile - 1) {   // diagonal tile: mask kv > q
                int ql = w * 16 + l16;
#pragma unroll
                for (int ct = 0; ct < 4; ct++)
#pragma unroll
                    for (int r = 0; r < 4; r++) {
                        int kvl = ct * 16 + quad * 4 + r;
                        if (kvl > ql) s[ct][r] = -30000.0f;
                    }
            }

            // p = exp2(s); vectorized P write: 4 consecutive kv per (ct) -> ushort4
#pragma unroll
            for (int ct = 0; ct < 4; ct++) {
                float p0 = exp2f(s[ct][0]);
                float p1 = exp2f(s[ct][1]);
                float p2 = exp2f(s[ct][2]);
                float p3 = exp2f(s[ct][3]);
                lr += (p0 + p1) + (p2 + p3);
                union { float f; unsigned u; } c0, c1, c2, c3;
                c0.f = p0; c1.f = p1; c2.f = p2; c3.f = p3;
                ushort4 pw;
                pw.x = (u16)(c0.u >> 16);
                pw.y = (u16)(c1.u >> 16);
                pw.z = (u16)(c2.u >> 16);
                pw.w = (u16)(c3.u >> 16);
                *(ushort4*)&Ps[w][l16][ct * 16 + quad * 4] = pw;
            }

            short8 ap0 = *(const short8*)&Ps[w][l16][quad * 8];
            short8 ap1 = *(const short8*)&Ps[w][l16][32 + quad * 8];
#pragma unroll
            for (int ct = 0; ct < 4; ct++) {
                short8 bv0 = *(const short8*)&VTs[db][ct * 16 + l16][quad * 8];
                short8 bv1 = *(const short8*)&VTs[db][ct * 16 + l16][32 + quad * 8];
                o[ct] = __builtin_amdgcn_mfma_f32_16x16x32_bf16(ap0, bv0, o[ct], 0, 0, 0);
                o[ct] = __builtin_amdgcn_mfma_f32_16x16x32_bf16(ap1, bv1, o[ct], 0, 0, 0);
            }
        }

        // reduce row sums across quads (lane holds q = w*16 + l16)
        float rs = lr;
        rs += __shfl_xor(rs, 16);
        rs += __shfl_xor(rs, 32);
        int gbase = lane & 48;
        float rinv[4];
#pragma unroll
        for (int r = 0; r < 4; r++)
            rinv[r] = 1.0f / __shfl(rs, gbase + quad * 4 + r);

        int q0 = qt * 64;
#pragma unroll
        for (int ct = 0; ct < 4; ct++) {
#pragma unroll
            for (int r = 0; r < 4; r++) {
                int q = q0 + w * 16 + quad * 4 + r;
                int d = h * 64 + ct * 16 + l16;
                AO[(size_t)(b * TT + q) * DD + d] = f2bf(o[ct][r] * rinv[r]);
            }
        }
    }
}

extern "C" void kernel_launch(void* const* d_in, const int* in_sizes, int n_in,
                              void* d_out, int out_size, void* d_ws, size_t ws_size,
                              hipStream_t stream) {
    const float* x  = (const float*)d_in[0];
    const float* Wq = (const float*)d_in[1];
    const float* Wk = (const float*)d_in[2];
    const float* Wv = (const float*)d_in[3];
    const float* Wo = (const float*)d_in[4];

    u16* xb  = (u16*)d_ws;                       // 8 MB  : x in bf16
    u16* WT  = xb + (size_t)MM * DD;             // 8 MB  : 4 transposed weights bf16
    u16* QKV = WT + (size_t)4 * DD * DD;         // 24 MB : Q,K (b,h,t,dh) + V^T (b,h,dh,t)
    u16* AO  = QKV + (size_t)3 * MM * DD;        // 8 MB  : attention out (B,T,D) bf16
    float* out = (float*)d_out;

    cast_x_k<<<dim3(MM * DD / 1024), 256, 0, stream>>>(x, xb);
    transw_k<<<dim3(32, 32, 4), dim3(32, 8), 0, stream>>>(Wq, Wk, Wv, Wo, WT);
    gemm_k<0, 64, 128><<<dim3(DD / 128, MM / 64, 3), 256, 0, stream>>>(xb, WT, QKV);
    attn_k<<<dim3(16, 32), 256, 0, stream>>>(QKV, AO);
    gemm_k<1, 64, 64><<<dim3(DD / 64, MM / 64, 1), 256, 0, stream>>>(AO, WT + (size_t)3 * DD * DD, out);
}

// Round 11
// 188.503 us; speedup vs baseline: 1.1668x; 1.1132x over previous
//
#include <hip/hip_runtime.h>

#define BB 2
#define TT 2048
#define DD 1024
#define HH 16
#define DHD 64
#define MM (BB*TT)   // 4096

typedef __attribute__((ext_vector_type(8))) short short8;
typedef __attribute__((ext_vector_type(4))) float float4v;
typedef unsigned short u16;

__device__ inline float bf2f(u16 u) {
    union { unsigned int i; float f; } v;
    v.i = ((unsigned int)u) << 16;
    return v.f;
}
__device__ inline u16 f2bf(float f) {
    union { float f; unsigned int i; } v;
    v.f = f;
    unsigned int x = v.i;
    unsigned int r = (x + 0x7fffu + ((x >> 16) & 1u)) >> 16;
    return (u16)r;
}

// ---------------- prep: cast x to bf16 ----------------
__global__ __launch_bounds__(256) void cast_x_k(const float* __restrict__ x,
                                                u16* __restrict__ xb) {
    int i = blockIdx.x * 256 + threadIdx.x;   // 4 elems/thread
    float4v v = ((const float4v*)x)[i];
    ushort4 o;
    o.x = f2bf(v[0]); o.y = f2bf(v[1]); o.z = f2bf(v[2]); o.w = f2bf(v[3]);
    ((ushort4*)xb)[i] = o;
}

// ---------------- prep: cast + transpose weights (K,N)->(N,K) bf16 ----------------
__global__ __launch_bounds__(256) void transw_k(const float* __restrict__ Wq,
                                                const float* __restrict__ Wk,
                                                const float* __restrict__ Wv,
                                                const float* __restrict__ Wo,
                                                u16* __restrict__ WT) {
    __shared__ u16 t[32][33];
    int wsel = blockIdx.z;
    const float* W = (wsel == 0) ? Wq : (wsel == 1) ? Wk : (wsel == 2) ? Wv : Wo;
    u16* o = WT + (size_t)wsel * DD * DD;
    int k0 = blockIdx.y * 32, n0 = blockIdx.x * 32;
    int tx = threadIdx.x, ty = threadIdx.y;   // 32 x 8
#pragma unroll
    for (int i = 0; i < 4; i++) {
        int k = ty + i * 8;
        t[k][tx] = f2bf(W[(size_t)(k0 + k) * DD + n0 + tx]);
    }
    __syncthreads();
#pragma unroll
    for (int i = 0; i < 4; i++) {
        int n = ty + i * 8;
        o[(size_t)(n0 + n) * DD + k0 + tx] = t[tx][n];
    }
}

// ---------------- GEMM: C(M,N) = A(bf16, MxK) * W (via WT: N,K bf16) ----------------
// r7-best skeleton (register prefetch -> explicit LDS writes, single buffer),
// upgraded: BK=64 (half the barriers), unpadded [row][64] LDS with XOR 16B-chunk
// swizzle (chunk c of row r stored at c^(r&7)) -> conflict-free b128 writes AND
// reads (read chunk q at q^(l16&7); row bases are multiples of 8 so r&7==l16&7).
// 4 waves 2x2, wave tile (TM/2)x(TN/2), 16x16x32 MFMA, 2 k-steps per iter.
// MODE 0: out = QKV workspace. z=0: Q (b,h,t,dh); z=1: K (b,h,t,dh); z=2: V^T (b,h,dh,t)
// MODE 1: out = fp32 (M, N) plain
template <int MODE, int TM, int TN>
__global__ __launch_bounds__(256) void gemm_k(const u16* __restrict__ A,
                                              const u16* __restrict__ WT0,
                                              void* __restrict__ outp) {
    const int K = DD, BK = 64;
    const int MT = TM / 32, NT = TN / 32;            // 16-row acc tiles per wave
    const int NS = (TM + TN) * (BK / 8) / 256;       // 16B chunks per thread

    int z = blockIdx.z;
    const u16* WT = WT0 + (size_t)z * DD * DD;
    int n0 = blockIdx.x * TN, m0 = blockIdx.y * TM;

    __shared__ u16 S[(TM + TN) * BK];                // A rows [0,TM), B rows [TM,TM+TN)

    int tid = threadIdx.x;
    int lane = tid & 63, w = tid >> 6;
    int wm = (w >> 1) * (TM / 2), wn = (w & 1) * (TN / 2);
    int quad = lane >> 4, l16 = lane & 15;

    // staging map: chunk id cid -> row r=cid/8, chunk c=cid%8; LDS chunk c^(r&7)
    const u16* gp[NS];
    u16* lp[NS];
#pragma unroll
    for (int j = 0; j < NS; j++) {
        int cid = tid + j * 256;
        int r = cid >> 3, c = cid & 7;
        lp[j] = S + r * BK + (c ^ (r & 7)) * 8;
        gp[j] = (r < TM ? A + (size_t)(m0 + r) * K
                        : WT + (size_t)(n0 + r - TM) * K) + c * 8;
    }
    int swz = l16 & 7;   // fragment-read swizzle (row bases are multiples of 8)

    float4v acc[MT][NT];
#pragma unroll
    for (int i = 0; i < MT; i++)
#pragma unroll
        for (int j = 0; j < NT; j++) acc[i][j] = (float4v)(0.0f);

    short8 pr[NS];
#pragma unroll
    for (int j = 0; j < NS; j++) pr[j] = *(const short8*)gp[j];   // prefetch tile 0

    const int NK = K / BK;
#pragma unroll 1
    for (int ki = 0; ki < NK; ki++) {
        __syncthreads();   // prior iter's fragment reads complete
#pragma unroll
        for (int j = 0; j < NS; j++) *(short8*)lp[j] = pr[j];
        __syncthreads();

        if (ki + 1 < NK) {   // prefetch next tile; in flight under MFMA
            int k0 = (ki + 1) * BK;
#pragma unroll
            for (int j = 0; j < NS; j++) pr[j] = *(const short8*)(gp[j] + k0);
        }

#pragma unroll
        for (int ks = 0; ks < 2; ks++) {
            int cq = ((ks * 4 + quad) ^ swz) * 8;
            short8 a[MT], b[NT];
#pragma unroll
            for (int mt = 0; mt < MT; mt++)
                a[mt] = *(const short8*)&S[(wm + mt * 16 + l16) * BK + cq];
#pragma unroll
            for (int nt = 0; nt < NT; nt++)
                b[nt] = *(const short8*)&S[(TM + wn + nt * 16 + l16) * BK + cq];
#pragma unroll
            for (int mt = 0; mt < MT; mt++)
#pragma unroll
                for (int nt = 0; nt < NT; nt++)
                    acc[mt][nt] = __builtin_amdgcn_mfma_f32_16x16x32_bf16(
                        a[mt], b[nt], acc[mt][nt], 0, 0, 0);
        }
    }

#pragma unroll
    for (int mt = 0; mt < MT; mt++) {
#pragma unroll
        for (int nt = 0; nt < NT; nt++) {
#pragma unroll
            for (int r = 0; r < 4; r++) {
                int m = m0 + wm + mt * 16 + quad * 4 + r;
                int n = n0 + wn + nt * 16 + l16;
                float v = acc[mt][nt][r];
                if constexpr (MODE == 0) {
                    int bb = m >> 11, t = m & 2047;
                    int h = n >> 6, dh = n & 63;
                    size_t idx;
                    if (z == 2)   // V stored transposed: (b,h,dh,t)
                        idx = (((size_t)2 * BB * HH + bb * HH + h) * DHD + dh) * TT + t;
                    else
                        idx = (((size_t)z * BB * HH + bb * HH + h) * TT + t) * DHD + dh;
                    ((u16*)outp)[idx] = f2bf(v);
                } else {
                    ((float*)outp)[(size_t)m * DD + n] = v;
                }
            }
        }
    }
}

// ---------------- flash attention (S^T trick, no-max, paired q-tiles, KV dbuf) ----------------
__global__ __launch_bounds__(256) void attn_k(const u16* __restrict__ QKV,
                                              u16* __restrict__ AO) {
    const u16* Q  = QKV;
    const u16* Kp = QKV + (size_t)MM * DD;
    const u16* Vp = QKV + (size_t)2 * MM * DD;   // V^T: per head [DHD][TT]
    int bh = blockIdx.y;
    int p  = blockIdx.x;          // 0..15
    int qA = p, qB = 31 - p;
    size_t hoff = (size_t)bh * TT * DHD;

    __shared__ u16 Qs[2][64][72];
    __shared__ u16 Ks[2][64][72];
    __shared__ u16 VTs[2][64][72];   // [dh][kv]
    __shared__ u16 Ps[4][16][72];    // per-wave [q][kv]

    int tid = threadIdx.x;
    int lane = tid & 63, w = tid >> 6;
    int quad = lane >> 4, l16 = lane & 15;

    int srow[4], scc[4];
#pragma unroll
    for (int i = 0; i < 4; i++) {
        int c = tid + i * 256;
        srow[i] = c >> 4;
        scc[i]  = (c & 15) * 4;
    }

    // stage BOTH Q tiles, pre-scaled by (1/sqrt(DH)) * log2(e)
    const float qscale = 0.125f * 1.4426950408889634f;
#pragma unroll
    for (int t = 0; t < 2; t++) {
        int q0 = (t ? qB : qA) * 64;
#pragma unroll
        for (int i = 0; i < 4; i++) {
            ushort4 v = *(const ushort4*)(Q + hoff + (size_t)(q0 + srow[i]) * DHD + scc[i]);
            ushort4 sv;
            sv.x = f2bf(bf2f(v.x) * qscale);
            sv.y = f2bf(bf2f(v.y) * qscale);
            sv.z = f2bf(bf2f(v.z) * qscale);
            sv.w = f2bf(bf2f(v.w) * qscale);
            *(ushort4*)&Qs[t][srow[i]][scc[i]] = sv;
        }
    }

    ushort4 kreg[4], vreg[4];
#pragma unroll
    for (int i = 0; i < 4; i++) {   // prefetch KV tile 0 (phase A)
        kreg[i] = *(const ushort4*)(Kp + hoff + (size_t)srow[i] * DHD + scc[i]);
        vreg[i] = *(const ushort4*)(Vp + hoff + (size_t)srow[i] * TT + scc[i]);
    }

    __syncthreads();   // Qs staged
    short8 aqA0 = *(const short8*)&Qs[0][w * 16 + l16][quad * 8];
    short8 aqA1 = *(const short8*)&Qs[0][w * 16 + l16][32 + quad * 8];
    short8 aqB0 = *(const short8*)&Qs[1][w * 16 + l16][quad * 8];
    short8 aqB1 = *(const short8*)&Qs[1][w * 16 + l16][32 + quad * 8];

    int b = bh >> 4, h = bh & 15;
    int it = 0;   // global iteration counter -> LDS buffer parity

#pragma unroll 1
    for (int phase = 0; phase < 2; phase++) {
        int qt = phase ? qB : qA;
        int ntile = qt + 1;
        short8 aq0 = phase ? aqB0 : aqA0;
        short8 aq1 = phase ? aqB1 : aqA1;

        float4v o[4];
#pragma unroll
        for (int i = 0; i < 4; i++) o[i] = (float4v)(0.0f);
        float lr = 0.0f;   // per-lane partial row sum (q = w*16 + l16)

#pragma unroll 1
        for (int jt = 0; jt < ntile; jt++, it++) {
            int db = it & 1;
#pragma unroll
            for (int i = 0; i < 4; i++) {
                *(ushort4*)&Ks[db][srow[i]][scc[i]]  = kreg[i];
                *(ushort4*)&VTs[db][srow[i]][scc[i]] = vreg[i];
            }
            __syncthreads();

            bool last = (phase == 1) && (jt == ntile - 1);
            if (!last) {
                int nj = (jt + 1 < ntile) ? (jt + 1) * 64 : 0;
#pragma unroll
                for (int i = 0; i < 4; i++) {
                    kreg[i] = *(const ushort4*)(Kp + hoff + (size_t)(nj + srow[i]) * DHD + scc[i]);
                    vreg[i] = *(const ushort4*)(Vp + hoff + (size_t)srow[i] * TT + nj + scc[i]);
                }
            }

            // S^T (64 kv x 16 q per wave) = K·Q^T: same LDS reads, swapped operands
            float4v s[4];
#pragma unroll
            for (int ct = 0; ct < 4; ct++) {
                short8 ak0 = *(const short8*)&Ks[db][ct * 16 + l16][quad * 8];
                short8 ak1 = *(const short8*)&Ks[db][ct * 16 + l16][32 + quad * 8];
                float4v sv = (float4v)(0.0f);
                sv = __builtin_amdgcn_mfma_f32_16x16x32_bf16(ak0, aq0, sv, 0, 0, 0);
                sv = __builtin_amdgcn_mfma_f32_16x16x32_bf16(ak1, aq1, sv, 0, 0, 0);
                s[ct] = sv;   // row=quad*4+r -> kv_local(ct block); col=l16 -> q_local
            }

            if (jt == ntile - 1) {   // diagonal tile: mask kv > q
                int ql = w * 16 + l16;
#pragma unroll
                for (int ct = 0; ct < 4; ct++)
#pragma unroll
                    for (int r = 0; r < 4; r++) {
                        int kvl = ct * 16 + quad * 4 + r;
                        if (kvl > ql) s[ct][r] = -30000.0f;
                    }
            }

            // p = exp2(s); vectorized P write: 4 consecutive kv per (ct) -> ushort4
#pragma unroll
            for (int ct = 0; ct < 4; ct++) {
                float p0 = exp2f(s[ct][0]);
                float p1 = exp2f(s[ct][1]);
                float p2 = exp2f(s[ct][2]);
                float p3 = exp2f(s[ct][3]);
                lr += (p0 + p1) + (p2 + p3);
                union { float f; unsigned u; } c0, c1, c2, c3;
                c0.f = p0; c1.f = p1; c2.f = p2; c3.f = p3;
                ushort4 pw;
                pw.x = (u16)(c0.u >> 16);
                pw.y = (u16)(c1.u >> 16);
                pw.z = (u16)(c2.u >> 16);
                pw.w = (u16)(c3.u >> 16);
                *(ushort4*)&Ps[w][l16][ct * 16 + quad * 4] = pw;
            }

            short8 ap0 = *(const short8*)&Ps[w][l16][quad * 8];
            short8 ap1 = *(const short8*)&Ps[w][l16][32 + quad * 8];
#pragma unroll
            for (int ct = 0; ct < 4; ct++) {
                short8 bv0 = *(const short8*)&VTs[db][ct * 16 + l16][quad * 8];
                short8 bv1 = *(const short8*)&VTs[db][ct * 16 + l16][32 + quad * 8];
                o[ct] = __builtin_amdgcn_mfma_f32_16x16x32_bf16(ap0, bv0, o[ct], 0, 0, 0);
                o[ct] = __builtin_amdgcn_mfma_f32_16x16x32_bf16(ap1, bv1, o[ct], 0, 0, 0);
            }
        }

        // reduce row sums across quads (lane holds q = w*16 + l16)
        float rs = lr;
        rs += __shfl_xor(rs, 16);
        rs += __shfl_xor(rs, 32);
        int gbase = lane & 48;
        float rinv[4];
#pragma unroll
        for (int r = 0; r < 4; r++)
            rinv[r] = 1.0f / __shfl(rs, gbase + quad * 4 + r);

        int q0 = qt * 64;
#pragma unroll
        for (int ct = 0; ct < 4; ct++) {
#pragma unroll
            for (int r = 0; r < 4; r++) {
                int q = q0 + w * 16 + quad * 4 + r;
                int d = h * 64 + ct * 16 + l16;
                AO[(size_t)(b * TT + q) * DD + d] = f2bf(o[ct][r] * rinv[r]);
            }
        }
    }
}

extern "C" void kernel_launch(void* const* d_in, const int* in_sizes, int n_in,
                              void* d_out, int out_size, void* d_ws, size_t ws_size,
                              hipStream_t stream) {
    const float* x  = (const float*)d_in[0];
    const float* Wq = (const float*)d_in[1];
    const float* Wk = (const float*)d_in[2];
    const float* Wv = (const float*)d_in[3];
    const float* Wo = (const float*)d_in[4];

    u16* xb  = (u16*)d_ws;                       // 8 MB  : x in bf16
    u16* WT  = xb + (size_t)MM * DD;             // 8 MB  : 4 transposed weights bf16
    u16* QKV = WT + (size_t)4 * DD * DD;         // 24 MB : Q,K (b,h,t,dh) + V^T (b,h,dh,t)
    u16* AO  = QKV + (size_t)3 * MM * DD;        // 8 MB  : attention out (B,T,D) bf16
    float* out = (float*)d_out;

    cast_x_k<<<dim3(MM * DD / 1024), 256, 0, stream>>>(x, xb);
    transw_k<<<dim3(32, 32, 4), dim3(32, 8), 0, stream>>>(Wq, Wk, Wv, Wo, WT);
    gemm_k<0, 128, 128><<<dim3(DD / 128, MM / 128, 3), 256, 0, stream>>>(xb, WT, QKV);
    attn_k<<<dim3(16, 32), 256, 0, stream>>>(QKV, AO);
    gemm_k<1, 64, 128><<<dim3(DD / 128, MM / 64, 1), 256, 0, stream>>>(AO, WT + (size_t)3 * DD * DD, out);
}

// Round 12
// 174.695 us; speedup vs baseline: 1.2590x; 1.0790x over previous
//
#include <hip/hip_runtime.h>

#define BB 2
#define TT 2048
#define DD 1024
#define HH 16
#define DHD 64
#define MM (BB*TT)   // 4096

typedef __attribute__((ext_vector_type(8))) short short8;
typedef __attribute__((ext_vector_type(4))) float float4v;
typedef unsigned short u16;

__device__ inline float bf2f(u16 u) {
    union { unsigned int i; float f; } v;
    v.i = ((unsigned int)u) << 16;
    return v.f;
}
__device__ inline u16 f2bf(float f) {
    union { float f; unsigned int i; } v;
    v.f = f;
    unsigned int x = v.i;
    unsigned int r = (x + 0x7fffu + ((x >> 16) & 1u)) >> 16;
    return (u16)r;
}

// ---------------- prep: cast x to bf16 ----------------
__global__ __launch_bounds__(256) void cast_x_k(const float* __restrict__ x,
                                                u16* __restrict__ xb) {
    int i = blockIdx.x * 256 + threadIdx.x;   // 4 elems/thread
    float4v v = ((const float4v*)x)[i];
    ushort4 o;
    o.x = f2bf(v[0]); o.y = f2bf(v[1]); o.z = f2bf(v[2]); o.w = f2bf(v[3]);
    ((ushort4*)xb)[i] = o;
}

// ---------------- prep: cast + transpose weights (K,N)->(N,K) bf16 ----------------
__global__ __launch_bounds__(256) void transw_k(const float* __restrict__ Wq,
                                                const float* __restrict__ Wk,
                                                const float* __restrict__ Wv,
                                                const float* __restrict__ Wo,
                                                u16* __restrict__ WT) {
    __shared__ u16 t[32][33];
    int wsel = blockIdx.z;
    const float* W = (wsel == 0) ? Wq : (wsel == 1) ? Wk : (wsel == 2) ? Wv : Wo;
    u16* o = WT + (size_t)wsel * DD * DD;
    int k0 = blockIdx.y * 32, n0 = blockIdx.x * 32;
    int tx = threadIdx.x, ty = threadIdx.y;   // 32 x 8
#pragma unroll
    for (int i = 0; i < 4; i++) {
        int k = ty + i * 8;
        t[k][tx] = f2bf(W[(size_t)(k0 + k) * DD + n0 + tx]);
    }
    __syncthreads();
#pragma unroll
    for (int i = 0; i < 4; i++) {
        int n = ty + i * 8;
        o[(size_t)(n0 + n) * DD + k0 + tx] = t[tx][n];
    }
}

// ---------------- GEMM (r11 winner, unchanged): BK=64, XOR-swizzled, reg-prefetch ------------
template <int MODE, int TM, int TN>
__global__ __launch_bounds__(256) void gemm_k(const u16* __restrict__ A,
                                              const u16* __restrict__ WT0,
                                              void* __restrict__ outp) {
    const int K = DD, BK = 64;
    const int MT = TM / 32, NT = TN / 32;
    const int NS = (TM + TN) * (BK / 8) / 256;

    int z = blockIdx.z;
    const u16* WT = WT0 + (size_t)z * DD * DD;
    int n0 = blockIdx.x * TN, m0 = blockIdx.y * TM;

    __shared__ u16 S[(TM + TN) * BK];

    int tid = threadIdx.x;
    int lane = tid & 63, w = tid >> 6;
    int wm = (w >> 1) * (TM / 2), wn = (w & 1) * (TN / 2);
    int quad = lane >> 4, l16 = lane & 15;

    const u16* gp[NS];
    u16* lp[NS];
#pragma unroll
    for (int j = 0; j < NS; j++) {
        int cid = tid + j * 256;
        int r = cid >> 3, c = cid & 7;
        lp[j] = S + r * BK + (c ^ (r & 7)) * 8;
        gp[j] = (r < TM ? A + (size_t)(m0 + r) * K
                        : WT + (size_t)(n0 + r - TM) * K) + c * 8;
    }
    int swz = l16 & 7;

    float4v acc[MT][NT];
#pragma unroll
    for (int i = 0; i < MT; i++)
#pragma unroll
        for (int j = 0; j < NT; j++) acc[i][j] = (float4v)(0.0f);

    short8 pr[NS];
#pragma unroll
    for (int j = 0; j < NS; j++) pr[j] = *(const short8*)gp[j];

    const int NK = K / BK;
#pragma unroll 1
    for (int ki = 0; ki < NK; ki++) {
        __syncthreads();
#pragma unroll
        for (int j = 0; j < NS; j++) *(short8*)lp[j] = pr[j];
        __syncthreads();

        if (ki + 1 < NK) {
            int k0 = (ki + 1) * BK;
#pragma unroll
            for (int j = 0; j < NS; j++) pr[j] = *(const short8*)(gp[j] + k0);
        }

#pragma unroll
        for (int ks = 0; ks < 2; ks++) {
            int cq = ((ks * 4 + quad) ^ swz) * 8;
            short8 a[MT], b[NT];
#pragma unroll
            for (int mt = 0; mt < MT; mt++)
                a[mt] = *(const short8*)&S[(wm + mt * 16 + l16) * BK + cq];
#pragma unroll
            for (int nt = 0; nt < NT; nt++)
                b[nt] = *(const short8*)&S[(TM + wn + nt * 16 + l16) * BK + cq];
#pragma unroll
            for (int mt = 0; mt < MT; mt++)
#pragma unroll
                for (int nt = 0; nt < NT; nt++)
                    acc[mt][nt] = __builtin_amdgcn_mfma_f32_16x16x32_bf16(
                        a[mt], b[nt], acc[mt][nt], 0, 0, 0);
        }
    }

#pragma unroll
    for (int mt = 0; mt < MT; mt++) {
#pragma unroll
        for (int nt = 0; nt < NT; nt++) {
#pragma unroll
            for (int r = 0; r < 4; r++) {
                int m = m0 + wm + mt * 16 + quad * 4 + r;
                int n = n0 + wn + nt * 16 + l16;
                float v = acc[mt][nt][r];
                if constexpr (MODE == 0) {
                    int bb = m >> 11, t = m & 2047;
                    int h = n >> 6, dh = n & 63;
                    size_t idx;
                    if (z == 2)   // V stored transposed: (b,h,dh,t)
                        idx = (((size_t)2 * BB * HH + bb * HH + h) * DHD + dh) * TT + t;
                    else
                        idx = (((size_t)z * BB * HH + bb * HH + h) * TT + t) * DHD + dh;
                    ((u16*)outp)[idx] = f2bf(v);
                } else {
                    ((float*)outp)[(size_t)m * DD + n] = v;
                }
            }
        }
    }
}

// ---------------- flash attention: merged-phase 512-thread block ----------------
// Waves 0-3 compute q-tile p, waves 4-7 q-tile 31-p, CONCURRENTLY sharing the
// staged K/V tiles (A's KV range is a subset of B's). Rounds/block = 32-p.
// Constant-sum pairing p = (by&16)? 15-t : t, t=(bx+by)&15 -> co-resident
// blocks (bid, bid+256) sum to exactly 49 rounds per CU.
// All LDS unpadded 64-wide with XOR 16B-chunk swizzle (0-conflict pattern,
// measured r8-r11); staging = one b128 per thread per tile, reg-prefetched.
// S^T trick + no-max softmax as before.
__global__ __launch_bounds__(512) void attn_k(const u16* __restrict__ QKV,
                                              u16* __restrict__ AO) {
    const u16* Q  = QKV;
    const u16* Kp = QKV + (size_t)MM * DD;
    const u16* Vp = QKV + (size_t)2 * MM * DD;   // V^T: per head [DHD][TT]
    int bh = blockIdx.y;
    int tswz = (blockIdx.x + blockIdx.y) & 15;
    int p = (blockIdx.y & 16) ? (15 - tswz) : tswz;
    int qA = p, qB = 31 - p;
    size_t hoff = (size_t)bh * TT * DHD;

    __shared__ u16 Qs[2][64 * 64];
    __shared__ u16 Ks[2][64 * 64];
    __shared__ u16 VTs[2][64 * 64];
    __shared__ u16 Ps[8][16 * 64];

    int tid = threadIdx.x;
    int lane = tid & 63, wv = tid >> 6;      // 8 waves
    int g = wv >> 2, w4 = wv & 3;            // group (phase), 16-row block
    int quad = lane >> 4, l16 = lane & 15;

    // staging: one 16B chunk per thread per 64x64 tile
    int sr = tid >> 3, sc = tid & 7;
    int sl = sr * 64 + ((sc ^ (sr & 7)) * 8);
    const u16* gK = Kp + hoff + (size_t)sr * DHD + sc * 8;
    const u16* gV = Vp + hoff + (size_t)sr * TT + sc * 8;

    // stage both Q tiles, scaled by (1/sqrt(DH)) * log2(e)
    const float qscale = 0.125f * 1.4426950408889634f;
#pragma unroll
    for (int t = 0; t < 2; t++) {
        int q0 = (t ? qB : qA) * 64;
        short8 v = *(const short8*)(Q + hoff + (size_t)(q0 + sr) * DHD + sc * 8);
        short8 sv;
#pragma unroll
        for (int e = 0; e < 8; e++) sv[e] = (short)f2bf(bf2f((u16)v[e]) * qscale);
        *(short8*)&Qs[t][sl] = sv;
    }

    short8 prK = *(const short8*)gK;   // prefetch KV tile 0
    short8 prV = *(const short8*)gV;

    __syncthreads();   // Q staged
    int cxs = l16 & 7;
    int fr = w4 * 16 + l16;   // my q-row within my tile
    short8 aq0 = *(const short8*)&Qs[g][fr * 64 + ((quad ^ cxs) * 8)];
    short8 aq1 = *(const short8*)&Qs[g][fr * 64 + (((4 + quad) ^ cxs) * 8)];

    int myqt = g ? qB : qA;
    int ntile = myqt + 1;     // my compute-active rounds
    int NR = qB + 1;          // total rounds (B's range covers A's)

    float4v o[4];
#pragma unroll
    for (int i = 0; i < 4; i++) o[i] = (float4v)(0.0f);
    float lr = 0.0f;

#pragma unroll 1
    for (int jt = 0; jt < NR; jt++) {
        int db = jt & 1;
        *(short8*)&Ks[db][sl]  = prK;
        *(short8*)&VTs[db][sl] = prV;
        __syncthreads();

        if (jt + 1 < NR) {   // prefetch next KV tile; in flight under compute
            size_t nj = (size_t)(jt + 1) * 64;
            prK = *(const short8*)(gK + nj * DHD);
            prV = *(const short8*)(gV + nj);
        }

        if (jt < ntile) {
            // S^T (64 kv x 16 q per wave) = K·Q^T
            float4v s[4];
#pragma unroll
            for (int ct = 0; ct < 4; ct++) {
                int kr = (ct * 16 + l16) * 64;
                short8 ak0 = *(const short8*)&Ks[db][kr + ((quad ^ cxs) * 8)];
                short8 ak1 = *(const short8*)&Ks[db][kr + (((4 + quad) ^ cxs) * 8)];
                float4v sv = (float4v)(0.0f);
                sv = __builtin_amdgcn_mfma_f32_16x16x32_bf16(ak0, aq0, sv, 0, 0, 0);
                sv = __builtin_amdgcn_mfma_f32_16x16x32_bf16(ak1, aq1, sv, 0, 0, 0);
                s[ct] = sv;   // lane: kv = ct*16+quad*4+r, q = fr
            }

            if (jt == myqt) {   // diagonal tile: mask kv > q (local coords)
                int ql = w4 * 16 + l16;
#pragma unroll
                for (int ct = 0; ct < 4; ct++)
#pragma unroll
                    for (int r = 0; r < 4; r++) {
                        int kvl = ct * 16 + quad * 4 + r;
                        if (kvl > ql) s[ct][r] = -30000.0f;
                    }
            }

            // p = exp2(s); P write (C->A layout) as swizzled 8B stores
#pragma unroll
            for (int ct = 0; ct < 4; ct++) {
                float p0 = exp2f(s[ct][0]);
                float p1 = exp2f(s[ct][1]);
                float p2 = exp2f(s[ct][2]);
                float p3 = exp2f(s[ct][3]);
                lr += (p0 + p1) + (p2 + p3);
                union { float f; unsigned u; } c0, c1, c2, c3;
                c0.f = p0; c1.f = p1; c2.f = p2; c3.f = p3;
                ushort4 pw;
                pw.x = (u16)(c0.u >> 16);
                pw.y = (u16)(c1.u >> 16);
                pw.z = (u16)(c2.u >> 16);
                pw.w = (u16)(c3.u >> 16);
                int chnk = (ct * 2 + (quad >> 1)) ^ cxs;
                *(ushort4*)&Ps[wv][l16 * 64 + chnk * 8 + (quad & 1) * 4] = pw;
            }

            short8 ap0 = *(const short8*)&Ps[wv][l16 * 64 + ((quad ^ cxs) * 8)];
            short8 ap1 = *(const short8*)&Ps[wv][l16 * 64 + (((4 + quad) ^ cxs) * 8)];
#pragma unroll
            for (int ct = 0; ct < 4; ct++) {
                int vr = (ct * 16 + l16) * 64;
                short8 bv0 = *(const short8*)&VTs[db][vr + ((quad ^ cxs) * 8)];
                short8 bv1 = *(const short8*)&VTs[db][vr + (((4 + quad) ^ cxs) * 8)];
                o[ct] = __builtin_amdgcn_mfma_f32_16x16x32_bf16(ap0, bv0, o[ct], 0, 0, 0);
                o[ct] = __builtin_amdgcn_mfma_f32_16x16x32_bf16(ap1, bv1, o[ct], 0, 0, 0);
            }
        }
    }

    // reduce row sums across quads (lane holds q = w4*16 + l16)
    float rs = lr;
    rs += __shfl_xor(rs, 16);
    rs += __shfl_xor(rs, 32);
    int gbase = lane & 48;
    float rinv[4];
#pragma unroll
    for (int r = 0; r < 4; r++)
        rinv[r] = 1.0f / __shfl(rs, gbase + quad * 4 + r);

    int b = bh >> 4, h = bh & 15;
    int q0 = myqt * 64;
#pragma unroll
    for (int ct = 0; ct < 4; ct++) {
#pragma unroll
        for (int r = 0; r < 4; r++) {
            int q = q0 + w4 * 16 + quad * 4 + r;
            int d = h * 64 + ct * 16 + l16;
            AO[(size_t)(b * TT + q) * DD + d] = f2bf(o[ct][r] * rinv[r]);
        }
    }
}

extern "C" void kernel_launch(void* const* d_in, const int* in_sizes, int n_in,
                              void* d_out, int out_size, void* d_ws, size_t ws_size,
                              hipStream_t stream) {
    const float* x  = (const float*)d_in[0];
    const float* Wq = (const float*)d_in[1];
    const float* Wk = (const float*)d_in[2];
    const float* Wv = (const float*)d_in[3];
    const float* Wo = (const float*)d_in[4];

    u16* xb  = (u16*)d_ws;                       // 8 MB  : x in bf16
    u16* WT  = xb + (size_t)MM * DD;             // 8 MB  : 4 transposed weights bf16
    u16* QKV = WT + (size_t)4 * DD * DD;         // 24 MB : Q,K (b,h,t,dh) + V^T (b,h,dh,t)
    u16* AO  = QKV + (size_t)3 * MM * DD;        // 8 MB  : attention out (B,T,D) bf16
    float* out = (float*)d_out;

    cast_x_k<<<dim3(MM * DD / 1024), 256, 0, stream>>>(x, xb);
    transw_k<<<dim3(32, 32, 4), dim3(32, 8), 0, stream>>>(Wq, Wk, Wv, Wo, WT);
    gemm_k<0, 128, 128><<<dim3(DD / 128, MM / 128, 3), 256, 0, stream>>>(xb, WT, QKV);
    attn_k<<<dim3(16, 32), 512, 0, stream>>>(QKV, AO);
    gemm_k<1, 64, 128><<<dim3(DD / 128, MM / 64, 1), 256, 0, stream>>>(AO, WT + (size_t)3 * DD * DD, out);
}